// Round 7
// baseline (81.930 us; speedup 1.0000x reference)
//
#include <hip/hip_runtime.h>

// GE2E loss, N=1024 spk, M=32 utt, D=512.
// v7: one-generation fused GEMM. Grid = 256 blocks (1/CU), each block owns
// 512 rows (mt-pair) x 256 cols; 16 K-tiles (BK=64) run as one continuous
// 4-phase-per-tile pipeline (m201 template). A is staged fp32->bf16 IN-KERNEL
// (global_load_dwordx4 issued 2-4 phases ahead -> pack -> linear
// ds_write_b128; swizzle on the source address). B staged via global_load_lds
// 2 tiles ahead. No ebf intermediate. prep = ck only. Per-panel row-max/own
// fold into a separate LDS region; cross-nt finish in rowred kernel.

#define N_SPK 1024
#define M_UTT 32
#define D_DIM 512
#define NROWS (N_SPK * M_UTT)   // 32768
#define NTILES 4                // 1024 / 256 col tiles
#define GRID_G 256

typedef __attribute__((ext_vector_type(8))) short short8v;  // 8 bf16
typedef __attribute__((ext_vector_type(4))) float f32x4;
typedef __attribute__((ext_vector_type(4))) unsigned int u32x4;

__device__ __forceinline__ unsigned short f2bf(float f) {
    union { float f; unsigned int u; } v; v.f = f;
    unsigned int u = v.u;
    u += 0x7fffu + ((u >> 16) & 1u);   // RNE
    return (unsigned short)(u >> 16);
}

// pack two f32 -> two bf16 (truncation; error << threshold margin)
__device__ __forceinline__ unsigned int pk2(float a, float b) {
    union { float f; unsigned int u; } ua, ub; ua.f = a; ub.f = b;
    return (ub.u & 0xFFFF0000u) | (ua.u >> 16);
}

__device__ __forceinline__ void gload_lds16(const void* g, void* l) {
    __builtin_amdgcn_global_load_lds(
        (const __attribute__((address_space(1))) unsigned int*)g,
        (__attribute__((address_space(3))) unsigned int*)l, 16, 0, 0);
}

__device__ __forceinline__ float sigmoidf(float x) {
    return 1.f / (1.f + __expf(-x));
}

template <int MH, int NH>
__device__ __forceinline__ void qmm(f32x4 (&acc)[8][4],
                                    const short8v (&a)[4][2],
                                    const short8v (&b)[2][2]) {
#pragma unroll
    for (int mf = 0; mf < 4; ++mf)
#pragma unroll
        for (int nf = 0; nf < 2; ++nf) {
            acc[MH * 4 + mf][NH * 2 + nf] = __builtin_amdgcn_mfma_f32_16x16x32_bf16(
                a[mf][0], b[nf][0], acc[MH * 4 + mf][NH * 2 + nf], 0, 0, 0);
            acc[MH * 4 + mf][NH * 2 + nf] = __builtin_amdgcn_mfma_f32_16x16x32_bf16(
                a[mf][1], b[nf][1], acc[MH * 4 + mf][NH * 2 + nf], 0, 0, 0);
        }
}

// ---- k1: ck bf16 (scaled by sgn(lw)/32) from fp32 emb ----------------------
__global__ void __launch_bounds__(256) ck_kernel(const float* __restrict__ emb,
                                                 const float* __restrict__ lnw,
                                                 unsigned short* __restrict__ ck) {
    __shared__ float part[2][D_DIM];
    const int n = blockIdx.x;
    const int t = threadIdx.x;
    const int d4 = (t & 127) * 4;
    const int mh = t >> 7;
    const float* base = emb + (size_t)n * M_UTT * D_DIM;

    float4 acc = {0.f, 0.f, 0.f, 0.f};
#pragma unroll
    for (int mm = 0; mm < 16; ++mm) {
        const int m = mh * 16 + mm;
        const float4 v = *reinterpret_cast<const float4*>(base + m * D_DIM + d4);
        acc.x += v.x; acc.y += v.y; acc.z += v.z; acc.w += v.w;
    }
    *reinterpret_cast<float4*>(&part[mh][d4]) = acc;
    __syncthreads();
    if (t < 128) {
        const float sgn = (lnw[0] >= 0.f) ? 1.f : -1.f;
        const float sc = sgn * (1.f / 32.f);
        const int d = t * 4;
        const float4 a = *reinterpret_cast<const float4*>(&part[0][d]);
        const float4 b = *reinterpret_cast<const float4*>(&part[1][d]);
        ushort4 o;
        o.x = f2bf((a.x + b.x) * sc); o.y = f2bf((a.y + b.y) * sc);
        o.z = f2bf((a.z + b.z) * sc); o.w = f2bf((a.w + b.w) * sc);
        *reinterpret_cast<ushort4*>(ck + (size_t)n * D_DIM + d) = o;
    }
}

// ---- k2: fused mt-pair 8-phase GEMM ----------------------------------------
__global__ void __launch_bounds__(512, 2)
gemm_kernel(const float* __restrict__ emb,
            const unsigned short* __restrict__ ck,
            float* __restrict__ maxo_part,
            float* __restrict__ own_part) {
    // buf[b]: A 256x64 bf16 at ushort [0,16384), B 256x64 bf16 at [16384,32768)
    // row r, logical 16B-chunk l stored at physical slot l^(r&7).
    __shared__ __align__(16) unsigned short buf[2][32768];   // 128 KB
    __shared__ float red[2][2][4][256];                      // 16 KB

    const int tid  = threadIdx.x;
    const int lane = tid & 63;
    const int wv   = tid >> 6;
    const int lo   = lane & 15;
    const int hi   = lane >> 4;
    const int wm   = wv >> 2;
    const int wn   = wv & 3;

    // XCD grouping: the 4 nt-siblings of a pair land on the same XCD
    const int raw   = blockIdx.x;
    const int P     = (raw & 7) * 8 + ((raw >> 3) >> 2);  // 0..63 row-pair
    const int ntb   = (raw >> 3) & 3;
    const int r0    = P * 512;
    const int n0    = ntb * 256;

    // staging source (pre-swizzled): chunk s=j*512+tid -> row j*64+(tid>>3)
    const int lsw = (tid & 7) ^ ((tid >> 3) & 7);
    const unsigned aoff0 = (unsigned)(r0 + (tid >> 3)) * 512u + (unsigned)lsw * 8u; // float idx
    const unsigned boff0 = (unsigned)(n0 + (tid >> 3)) * 512u + (unsigned)lsw * 8u; // ushort idx
    const int dA = tid * 8;            // ushort idx, + j*4096
    const int dB = 16384 + tid * 8;

    // read addressing
    const int ph0   = (hi ^ (lo & 7)) * 8;        // ushort offs, kk=0
    const int ph1   = ((4 + hi) ^ (lo & 7)) * 8;  // kk=1
    const int abase = (wm * 128 + lo) * 64;
    const int bbase = 16384 + (wn * 64 + lo) * 64;

    float4 ga[4], gb[4];

    // ---- prologue: gA(0) all 4 chunks; B(0); B(1); write A(0); gate ----
#pragma unroll
    for (int j = 0; j < 2; ++j) {
        ga[2 * j]     = *reinterpret_cast<const float4*>(emb + aoff0 + j * 32768u);
        ga[2 * j + 1] = *reinterpret_cast<const float4*>(emb + aoff0 + j * 32768u + 4u);
        gb[2 * j]     = *reinterpret_cast<const float4*>(emb + aoff0 + (j + 2) * 32768u);
        gb[2 * j + 1] = *reinterpret_cast<const float4*>(emb + aoff0 + (j + 2) * 32768u + 4u);
    }
#pragma unroll
    for (int j = 0; j < 4; ++j)
        gload_lds16(ck + boff0 + j * 32768u, &buf[0][dB + j * 4096]);
#pragma unroll
    for (int j = 0; j < 4; ++j)
        gload_lds16(ck + boff0 + j * 32768u + 64u, &buf[1][dB + j * 4096]);
    {
        u32x4 w0 = {pk2(ga[0].x, ga[0].y), pk2(ga[0].z, ga[0].w),
                    pk2(ga[1].x, ga[1].y), pk2(ga[1].z, ga[1].w)};
        u32x4 w1 = {pk2(ga[2].x, ga[2].y), pk2(ga[2].z, ga[2].w),
                    pk2(ga[3].x, ga[3].y), pk2(ga[3].z, ga[3].w)};
        u32x4 w2 = {pk2(gb[0].x, gb[0].y), pk2(gb[0].z, gb[0].w),
                    pk2(gb[1].x, gb[1].y), pk2(gb[1].z, gb[1].w)};
        u32x4 w3 = {pk2(gb[2].x, gb[2].y), pk2(gb[2].z, gb[2].w),
                    pk2(gb[3].x, gb[3].y), pk2(gb[3].z, gb[3].w)};
        *reinterpret_cast<u32x4*>(&buf[0][dA])         = w0;
        *reinterpret_cast<u32x4*>(&buf[0][dA + 4096])  = w1;
        *reinterpret_cast<u32x4*>(&buf[0][dA + 8192])  = w2;
        *reinterpret_cast<u32x4*>(&buf[0][dA + 12288]) = w3;
    }
    asm volatile("s_waitcnt lgkmcnt(0)" ::: "memory");
    asm volatile("s_waitcnt vmcnt(4)" ::: "memory");   // B(0) landed, B(1) flying
    __builtin_amdgcn_s_barrier();
    __builtin_amdgcn_sched_barrier(0);

    f32x4 acc[8][4];
#pragma unroll
    for (int am = 0; am < 8; ++am)
#pragma unroll
        for (int an = 0; an < 4; ++an) acc[am][an] = (f32x4){0.f, 0.f, 0.f, 0.f};

    short8v afr[4][2], b0c[2][2], b1c[2][2];
    const float NEG = -1e30f;

#pragma unroll
    for (int tau = 0; tau < 16; ++tau) {
        const int cur = tau & 1;
        const unsigned short* bp  = &buf[cur][0];
        unsigned short*       bpn = &buf[cur ^ 1][0];
        const unsigned kA = (unsigned)((((tau + 1) >> 3) * 131072) + (((tau + 1) & 7) * 64));
        const unsigned kB = (unsigned)(((tau + 2) & 7) * 64);

        // ---- phase 0: issue gA(t+1) set0; read a(mh0), b(nh0); Q00 ----
        if (tau < 15) {
#pragma unroll
            for (int j = 0; j < 2; ++j) {
                ga[2 * j]     = *reinterpret_cast<const float4*>(emb + aoff0 + kA + j * 32768u);
                ga[2 * j + 1] = *reinterpret_cast<const float4*>(emb + aoff0 + kA + j * 32768u + 4u);
            }
        }
#pragma unroll
        for (int mf = 0; mf < 4; ++mf) {
            afr[mf][0] = *reinterpret_cast<const short8v*>(bp + abase + mf * 1024 + ph0);
            afr[mf][1] = *reinterpret_cast<const short8v*>(bp + abase + mf * 1024 + ph1);
        }
#pragma unroll
        for (int nf = 0; nf < 2; ++nf) {
            b0c[nf][0] = *reinterpret_cast<const short8v*>(bp + bbase + nf * 1024 + ph0);
            b0c[nf][1] = *reinterpret_cast<const short8v*>(bp + bbase + nf * 1024 + ph1);
        }
        __builtin_amdgcn_s_barrier();
        __builtin_amdgcn_s_setprio(1);
        qmm<0, 0>(acc, afr, b0c);
        __builtin_amdgcn_s_setprio(0);
        __builtin_amdgcn_s_barrier();

        // ---- phase 1: issue gA(t+1) set1; read b(nh1); Q01 ----
        if (tau < 15) {
#pragma unroll
            for (int j = 0; j < 2; ++j) {
                gb[2 * j]     = *reinterpret_cast<const float4*>(emb + aoff0 + kA + (j + 2) * 32768u);
                gb[2 * j + 1] = *reinterpret_cast<const float4*>(emb + aoff0 + kA + (j + 2) * 32768u + 4u);
            }
        }
#pragma unroll
        for (int nf = 0; nf < 2; ++nf) {
            b1c[nf][0] = *reinterpret_cast<const short8v*>(bp + bbase + 2048 + nf * 1024 + ph0);
            b1c[nf][1] = *reinterpret_cast<const short8v*>(bp + bbase + 2048 + nf * 1024 + ph1);
        }
        __builtin_amdgcn_s_barrier();
        __builtin_amdgcn_s_setprio(1);
        qmm<0, 1>(acc, afr, b1c);
        __builtin_amdgcn_s_setprio(0);
        __builtin_amdgcn_s_barrier();

        // ---- phase 2: issue B(t+2) DMA; write A(t+1) set0; read a(mh1); Q11 ----
        if (tau < 14) {
#pragma unroll
            for (int j = 0; j < 4; ++j)
                gload_lds16(ck + boff0 + kB + j * 32768u, &buf[cur][dB + j * 4096]);
        }
        if (tau < 15) {
            u32x4 w0 = {pk2(ga[0].x, ga[0].y), pk2(ga[0].z, ga[0].w),
                        pk2(ga[1].x, ga[1].y), pk2(ga[1].z, ga[1].w)};
            u32x4 w1 = {pk2(ga[2].x, ga[2].y), pk2(ga[2].z, ga[2].w),
                        pk2(ga[3].x, ga[3].y), pk2(ga[3].z, ga[3].w)};
            *reinterpret_cast<u32x4*>(bpn + dA)        = w0;
            *reinterpret_cast<u32x4*>(bpn + dA + 4096) = w1;
        }
#pragma unroll
        for (int mf = 0; mf < 4; ++mf) {
            afr[mf][0] = *reinterpret_cast<const short8v*>(bp + abase + 4096 + mf * 1024 + ph0);
            afr[mf][1] = *reinterpret_cast<const short8v*>(bp + abase + 4096 + mf * 1024 + ph1);
        }
        __builtin_amdgcn_s_barrier();
        __builtin_amdgcn_s_setprio(1);
        qmm<1, 1>(acc, afr, b1c);
        __builtin_amdgcn_s_setprio(0);
        __builtin_amdgcn_s_barrier();

        // ---- phase 3: write A(t+1) set1; drain ds_writes; Q10 ----
        if (tau < 15) {
            u32x4 w2 = {pk2(gb[0].x, gb[0].y), pk2(gb[0].z, gb[0].w),
                        pk2(gb[1].x, gb[1].y), pk2(gb[1].z, gb[1].w)};
            u32x4 w3 = {pk2(gb[2].x, gb[2].y), pk2(gb[2].z, gb[2].w),
                        pk2(gb[3].x, gb[3].y), pk2(gb[3].z, gb[3].w)};
            *reinterpret_cast<u32x4*>(bpn + dA + 8192)  = w2;
            *reinterpret_cast<u32x4*>(bpn + dA + 12288) = w3;
        }
        asm volatile("s_waitcnt lgkmcnt(0)" ::: "memory");
        __builtin_amdgcn_s_barrier();
        __builtin_amdgcn_s_setprio(1);
        qmm<1, 0>(acc, afr, b0c);
        __builtin_amdgcn_s_setprio(0);
        __builtin_amdgcn_s_barrier();
        __builtin_amdgcn_sched_barrier(0);

        // ---- panel boundary: fold panel 0, reset acc (shfl + red LDS only) ----
        if (tau == 7 || tau == 15) {
            const int pan = tau >> 3;
#pragma unroll
            for (int am = 0; am < 8; ++am) {
#pragma unroll
                for (int reg = 0; reg < 4; ++reg) {
                    const int rl   = wm * 128 + am * 16 + hi * 4 + reg;
                    const int rowg = r0 + pan * 256 + rl;
                    const int spk  = rowg >> 5;
                    float m = NEG, o = NEG;
#pragma unroll
                    for (int an = 0; an < 4; ++an) {
                        const int col = n0 + wn * 64 + an * 16 + lo;
                        const float v = acc[am][an][reg];
                        const bool dg = (col == spk);
                        o = dg ? v : o;
                        m = fmaxf(m, dg ? NEG : v);
                    }
#pragma unroll
                    for (int mask = 1; mask < 16; mask <<= 1) {
                        m = fmaxf(m, __shfl_xor(m, mask));
                        o = fmaxf(o, __shfl_xor(o, mask));
                    }
                    if (lo == 0) {
                        red[pan][0][wn][rl] = m;
                        red[pan][1][wn][rl] = o;
                    }
                }
            }
            if (tau == 7) {
#pragma unroll
                for (int am = 0; am < 8; ++am)
#pragma unroll
                    for (int an = 0; an < 4; ++an)
                        acc[am][an] = (f32x4){0.f, 0.f, 0.f, 0.f};
            }
        }
    }

    // ---- final combine + global writes ----
    __syncthreads();
    if (tid < 256) {
#pragma unroll
        for (int pan = 0; pan < 2; ++pan) {
            const float mo = fmaxf(fmaxf(red[pan][0][0][tid], red[pan][0][1][tid]),
                                   fmaxf(red[pan][0][2][tid], red[pan][0][3][tid]));
            maxo_part[(size_t)ntb * NROWS + r0 + pan * 256 + tid] = mo;
            const int mtp = P * 2 + pan;
            if (ntb == (mtp >> 5)) {
                const float op = fmaxf(fmaxf(red[pan][1][0][tid], red[pan][1][1][tid]),
                                       fmaxf(red[pan][1][2][tid], red[pan][1][3][tid]));
                own_part[r0 + pan * 256 + tid] = op;
            }
        }
    }
}

// ---- k3: per-row finish: combine 4 tile-maxes, sigmoid, loss/corr ---------
__global__ void __launch_bounds__(256) rowred_kernel(const float* __restrict__ maxo_part,
                                                     const float* __restrict__ own_part,
                                                     const float* __restrict__ lnw,
                                                     const float* __restrict__ lnb,
                                                     float* __restrict__ partsum) {
    const int r = blockIdx.x * 256 + threadIdx.x;
    const float lw = lnw[0], lb = lnb[0];
    const float sgn = (lw >= 0.f) ? 1.f : -1.f;
    const float alw = fabsf(lw);

    float mo = maxo_part[r];
#pragma unroll
    for (int nt2 = 1; nt2 < NTILES; ++nt2)
        mo = fmaxf(mo, maxo_part[(size_t)nt2 * NROWS + r]);
    const float ownp  = own_part[r];          // sgn-scaled raw dot e.ck_own
    const float s_own = sgn * ownp;
    const float ex    = (32.f * s_own - 1.f) * (1.f / 31.f);
    const float own_s = sigmoidf(lw * ex + lb);
    const float mo_s  = sigmoidf(alw * mo + lb);
    float loss = 1.f - own_s + mo_s;
    float corr = (sgn * ex >= mo) ? 1.f : 0.f;

#pragma unroll
    for (int mask = 1; mask < 64; mask <<= 1) {
        loss += __shfl_xor(loss, mask);
        corr += __shfl_xor(corr, mask);
    }
    __shared__ float sl[4], sc[4];
    const int wv = threadIdx.x >> 6;
    if ((threadIdx.x & 63) == 0) { sl[wv] = loss; sc[wv] = corr; }
    __syncthreads();
    if (threadIdx.x == 0) {
        partsum[blockIdx.x]       = sl[0] + sl[1] + sl[2] + sl[3];
        partsum[128 + blockIdx.x] = sc[0] + sc[1] + sc[2] + sc[3];
    }
}

// ---- k4: final scalar reduce ----------------------------------------------
__global__ void __launch_bounds__(128) final_kernel(const float* __restrict__ partsum,
                                                    float* __restrict__ out) {
    const int t = threadIdx.x;
    float l = partsum[t];
    float c = partsum[128 + t];
#pragma unroll
    for (int mask = 1; mask < 64; mask <<= 1) {
        l += __shfl_xor(l, mask);
        c += __shfl_xor(c, mask);
    }
    __shared__ float sl[2], sc[2];
    if ((t & 63) == 0) { sl[t >> 6] = l; sc[t >> 6] = c; }
    __syncthreads();
    if (t == 0) {
        out[0] = (sl[0] + sl[1]) * (1.f / (float)NROWS);
        out[1] = (sc[0] + sc[1]) * (1.f / (float)NROWS);
    }
}

extern "C" void kernel_launch(void* const* d_in, const int* in_sizes, int n_in,
                              void* d_out, int out_size, void* d_ws, size_t ws_size,
                              hipStream_t stream) {
    (void)in_sizes; (void)n_in; (void)out_size; (void)ws_size;
    const float* emb = (const float*)d_in[0];
    const float* lnw = (const float*)d_in[3];
    const float* lnb = (const float*)d_in[4];
    float* out = (float*)d_out;

    char* ws = (char*)d_ws;
    unsigned short* ck = (unsigned short*)ws;                           // 1 MB
    float* maxo_part = (float*)(ws + (size_t)N_SPK * D_DIM * 2);        // 512 KB
    float* own_part  = (float*)((char*)maxo_part + (size_t)NTILES * NROWS * 4); // 128 KB
    float* partsum   = (float*)((char*)own_part + (size_t)NROWS * 4);   // 1 KB

    ck_kernel<<<N_SPK, 256, 0, stream>>>(emb, lnw, ck);
    gemm_kernel<<<GRID_G, 512, 0, stream>>>(emb, ck, maxo_part, own_part);
    rowred_kernel<<<NROWS / 256, 256, 0, stream>>>(maxo_part, own_part, lnw, lnb, partsum);
    final_kernel<<<1, 128, 0, stream>>>(partsum, out);
}